// Round 2
// baseline (48401.184 us; speedup 1.0000x reference)
//
#include <hip/hip_runtime.h>

#define B_ 64
#define T_ 512
#define D_ 1024
#define H_ 1024
#define NG_ 4096   // 4*H

// ---------------- h transpose helpers ----------------
// hT[k][b] = h[b][k]
__global__ __launch_bounds__(256) void k_trans_h_fwd(const float* __restrict__ h,
                                                     float* __restrict__ hT) {
  int idx = blockIdx.x * 256 + threadIdx.x;  // idx = k*64 + b
  int b = idx & 63;
  int k = idx >> 6;
  hT[idx] = h[b * H_ + k];
}

// h[b][k] = hT[k][b]
__global__ __launch_bounds__(256) void k_trans_h_back(const float* __restrict__ hT,
                                                      float* __restrict__ h) {
  int idx = blockIdx.x * 256 + threadIdx.x;  // idx = b*1024 + k
  int k = idx & (H_ - 1);
  int b = idx >> 10;
  h[idx] = hT[k * 64 + b];
}

// ---------------- Gx = x@Wi + bias, batched over a time chunk ----------------
// Grid: (256 col-blocks, Tc). Block: 512 threads (8 waves).
// Each block: 64 b x 16 gate-cols (4 h-cols x 4 gates) for one t.
// Output layout: gx[trel][cb][b][c*4+g]  (exactly the step kernel's read order)
__global__ __launch_bounds__(512) void k_gx(
    const float* __restrict__ x,     // [64][512][1024]
    const float* __restrict__ Wi,    // [1024][4096]
    const float* __restrict__ bias,  // [4096]
    float* __restrict__ gx,          // [Tc][256][64][16]
    int t0) {
  __shared__ float xt[64 * 65];        // [k within tile][b], padded
  __shared__ float red[8 * 64 * 17];   // [w][b][c*4+g], padded

  const int tid = threadIdx.x;
  const int lane = tid & 63;
  const int w = tid >> 6;
  const int hbase = blockIdx.x * 4;
  const int t = t0 + blockIdx.y;

  float acc[4][4];
#pragma unroll
  for (int c = 0; c < 4; ++c)
#pragma unroll
    for (int g = 0; g < 4; ++g) acc[c][g] = 0.f;

  for (int kt = 0; kt < 16; ++kt) {  // 16 tiles of 64 k
    __syncthreads();
    // stage x tile: rows b=0..63, cols d = kt*64 .. +63, coalesced reads
#pragma unroll
    for (int p = 0; p < 8; ++p) {
      int r = p * 8 + (tid >> 6);        // b row 0..63
      int dd = tid & 63;                 // d within tile
      xt[dd * 65 + r] = x[(size_t)r * (T_ * D_) + (size_t)t * D_ + kt * 64 + dd];
    }
    __syncthreads();
    // MAC: wave w handles kk in [w*8, w*8+8)
    const int kkbase = w * 8;
#pragma unroll
    for (int kk = kkbase; kk < kkbase + 8; ++kk) {
      const int k = kt * 64 + kk;
      const float xv = xt[kk * 65 + lane];
#pragma unroll
      for (int g = 0; g < 4; ++g) {
        const float4 wi = *(const float4*)(Wi + (size_t)k * NG_ + g * H_ + hbase);
        acc[0][g] = fmaf(xv, wi.x, acc[0][g]);
        acc[1][g] = fmaf(xv, wi.y, acc[1][g]);
        acc[2][g] = fmaf(xv, wi.z, acc[2][g]);
        acc[3][g] = fmaf(xv, wi.w, acc[3][g]);
      }
    }
  }

  // cross-wave reduce
#pragma unroll
  for (int c = 0; c < 4; ++c)
#pragma unroll
    for (int g = 0; g < 4; ++g) red[(w * 64 + lane) * 17 + c * 4 + g] = acc[c][g];
  __syncthreads();

  if (tid < 256) {
    const int b = tid >> 2;
    const int c = tid & 3;
    const int h = hbase + c;
    float4 v;
    float* vp = &v.x;
#pragma unroll
    for (int g = 0; g < 4; ++g) {
      float s = bias[g * H_ + h];
#pragma unroll
      for (int ww = 0; ww < 8; ++ww) s += red[(ww * 64 + b) * 17 + c * 4 + g];
      vp[g] = s;
    }
    *(float4*)(gx + ((size_t)(blockIdx.y * 256 + blockIdx.x) * 64 + b) * 16 + c * 4) = v;
  }
}

// ---------------- one LSTM step: gates = gx + hT@Wh, elementwise ----------------
// Grid: 256 blocks x 512 threads (8 waves, k-split 8).
__global__ __launch_bounds__(512) void k_step(
    const float* __restrict__ Wh,     // [1024][4096]
    const float* __restrict__ gx_t,   // [256][64][16] for this t (bias folded)
    const float* __restrict__ hT_in,  // [1024][64]
    float* __restrict__ hT_out,       // [1024][64]
    float* __restrict__ c_state,      // [64][1024] in-place
    float* __restrict__ ys_t)         // out ys + t*H, stride T*H per b
{
  __shared__ float red[8 * 64 * 17];
  const int tid = threadIdx.x;
  const int lane = tid & 63;
  const int w = tid >> 6;
  const int hbase = blockIdx.x * 4;

  float acc[4][4];
#pragma unroll
  for (int c = 0; c < 4; ++c)
#pragma unroll
    for (int g = 0; g < 4; ++g) acc[c][g] = 0.f;

  const int k0 = w * 128;
#pragma unroll 4
  for (int k = k0; k < k0 + 128; ++k) {
    const float hv = hT_in[k * 64 + lane];
#pragma unroll
    for (int g = 0; g < 4; ++g) {
      const float4 wh = *(const float4*)(Wh + (size_t)k * NG_ + g * H_ + hbase);
      acc[0][g] = fmaf(hv, wh.x, acc[0][g]);
      acc[1][g] = fmaf(hv, wh.y, acc[1][g]);
      acc[2][g] = fmaf(hv, wh.z, acc[2][g]);
      acc[3][g] = fmaf(hv, wh.w, acc[3][g]);
    }
  }

#pragma unroll
  for (int c = 0; c < 4; ++c)
#pragma unroll
    for (int g = 0; g < 4; ++g) red[(w * 64 + lane) * 17 + c * 4 + g] = acc[c][g];
  __syncthreads();

  if (tid < 256) {
    const int b = tid >> 2;
    const int c = tid & 3;
    const int h = hbase + c;
    const float4 gxv = *(const float4*)(gx_t + ((size_t)blockIdx.x * 64 + b) * 16 + c * 4);
    const float* gp = &gxv.x;
    float v[4];
#pragma unroll
    for (int g = 0; g < 4; ++g) {
      float s = gp[g];
#pragma unroll
      for (int ww = 0; ww < 8; ++ww) s += red[(ww * 64 + b) * 17 + c * 4 + g];
      v[g] = s;
    }
    const float cold = c_state[b * H_ + h];
    const float si = 1.f / (1.f + expf(-v[0]));
    const float sf = 1.f / (1.f + expf(-v[1]));
    const float gt = tanhf(v[2]);
    const float so = 1.f / (1.f + expf(-v[3]));
    const float cn = sf * cold + si * gt;
    const float hn = so * tanhf(cn);
    c_state[b * H_ + h] = cn;
    hT_out[h * 64 + b] = hn;
    ys_t[(size_t)b * (T_ * H_) + h] = hn;
  }
}

// ---------------- fallback: round-1 fused step (x read directly) ----------------
__global__ __launch_bounds__(512) void k_lstm_step_fused(
    const float* __restrict__ xsrc,   // x + t*D_
    const float* __restrict__ Wi, const float* __restrict__ Wh,
    const float* __restrict__ bias,
    const float* __restrict__ hT_in, float* __restrict__ hT_out,
    float* __restrict__ c_state, float* __restrict__ ys_t) {
  __shared__ float red[8 * 64 * 17];
  const int tid = threadIdx.x;
  const int lane = tid & 63;
  const int w = tid >> 6;
  const int hbase = blockIdx.x * 4;
  float acc[4][4];
#pragma unroll
  for (int c = 0; c < 4; ++c)
#pragma unroll
    for (int g = 0; g < 4; ++g) acc[c][g] = 0.f;
  const int k0 = w * 128;
#pragma unroll 2
  for (int k = k0; k < k0 + 128; ++k) {
    const float hv = hT_in[k * 64 + lane];
    const float xv = xsrc[(size_t)lane * (T_ * D_) + k];
#pragma unroll
    for (int g = 0; g < 4; ++g) {
      const float4 wh = *(const float4*)(Wh + (size_t)k * NG_ + g * H_ + hbase);
      const float4 wi = *(const float4*)(Wi + (size_t)k * NG_ + g * H_ + hbase);
      acc[0][g] = fmaf(hv, wh.x, acc[0][g]);
      acc[1][g] = fmaf(hv, wh.y, acc[1][g]);
      acc[2][g] = fmaf(hv, wh.z, acc[2][g]);
      acc[3][g] = fmaf(hv, wh.w, acc[3][g]);
      acc[0][g] = fmaf(xv, wi.x, acc[0][g]);
      acc[1][g] = fmaf(xv, wi.y, acc[1][g]);
      acc[2][g] = fmaf(xv, wi.z, acc[2][g]);
      acc[3][g] = fmaf(xv, wi.w, acc[3][g]);
    }
  }
#pragma unroll
  for (int c = 0; c < 4; ++c)
#pragma unroll
    for (int g = 0; g < 4; ++g) red[(w * 64 + lane) * 17 + c * 4 + g] = acc[c][g];
  __syncthreads();
  if (tid < 256) {
    const int b = tid >> 2;
    const int c = tid & 3;
    const int h = hbase + c;
    float v[4];
#pragma unroll
    for (int g = 0; g < 4; ++g) {
      float s = bias[g * H_ + h];
#pragma unroll
      for (int ww = 0; ww < 8; ++ww) s += red[(ww * 64 + b) * 17 + c * 4 + g];
      v[g] = s;
    }
    const float cold = c_state[b * H_ + h];
    const float si = 1.f / (1.f + expf(-v[0]));
    const float sf = 1.f / (1.f + expf(-v[1]));
    const float gt = tanhf(v[2]);
    const float so = 1.f / (1.f + expf(-v[3]));
    const float cn = sf * cold + si * gt;
    const float hn = so * tanhf(cn);
    c_state[b * H_ + h] = cn;
    hT_out[h * 64 + b] = hn;
    ys_t[(size_t)b * (T_ * H_) + h] = hn;
  }
}

extern "C" void kernel_launch(void* const* d_in, const int* in_sizes, int n_in,
                              void* d_out, int out_size, void* d_ws, size_t ws_size,
                              hipStream_t stream) {
  const float* c0   = (const float*)d_in[0];
  const float* h0   = (const float*)d_in[1];
  const float* x    = (const float*)d_in[2];
  const float* Wi   = (const float*)d_in[3];
  const float* Wh   = (const float*)d_in[4];
  const float* bias = (const float*)d_in[5];

  float* out     = (float*)d_out;
  float* c_state = out;                 // [64][1024] final c (in-place state)
  float* h_final = out + B_ * H_;       // [64][1024] final h
  float* ys      = out + 2 * B_ * H_;   // [64][512][1024]

  const size_t hbytes = (size_t)B_ * H_ * sizeof(float);
  float* hA = (float*)d_ws;
  float* hB = hA + B_ * H_;
  float* gxbuf = hB + B_ * H_;

  const size_t slice = (size_t)256 * 64 * 16 * sizeof(float);  // 1 MB per t
  size_t avail = (ws_size > 2 * hbytes) ? ws_size - 2 * hbytes : 0;
  int Tc = (int)(avail / slice);
  if (Tc > T_) Tc = T_;

  hipMemcpyAsync(c_state, c0, hbytes, hipMemcpyDeviceToDevice, stream);
  k_trans_h_fwd<<<B_ * H_ / 256, 256, 0, stream>>>(h0, hA);

  if (Tc >= 1) {
    for (int t0 = 0; t0 < T_; t0 += Tc) {
      const int tc = (T_ - t0 < Tc) ? (T_ - t0) : Tc;
      dim3 gg(256, tc);
      k_gx<<<gg, 512, 0, stream>>>(x, Wi, bias, gxbuf, t0);
      for (int t = t0; t < t0 + tc; ++t) {
        const float* hin = (t & 1) ? hB : hA;
        float* hout      = (t & 1) ? hA : hB;
        k_step<<<256, 512, 0, stream>>>(
            Wh, gxbuf + (size_t)(t - t0) * 256 * 64 * 16, hin, hout, c_state,
            ys + (size_t)t * H_);
      }
    }
  } else {
    for (int t = 0; t < T_; ++t) {
      const float* hin = (t & 1) ? hB : hA;
      float* hout      = (t & 1) ? hA : hB;
      k_lstm_step_fused<<<256, 512, 0, stream>>>(
          x + (size_t)t * D_, Wi, Wh, bias, hin, hout, c_state,
          ys + (size_t)t * H_);
    }
  }
  // T_ even -> last write went to hA
  k_trans_h_back<<<B_ * H_ / 256, 256, 0, stream>>>(hA, h_final);
}